// Round 1
// baseline (15.536 us; speedup 1.0000x reference)
//
#include <hip/hip_runtime.h>
#include <hip/hip_bf16.h>

// Embedding lookup: out[row, :] = weight[idx[row], :]
//   idxes:  [BATCH*SEQ] = 8192 int32
//   weight: [50257, 1024] float32
//   out:    [8192, 1024] float32
//
// Pure gather, memory-bound. One block (256 threads) per output row;
// each thread copies one float4 (16 B) -> fully coalesced 1024 B per wave
// per instruction.

#define FEATURES 1024
#define N_ROWS   (4 * 2048)

__global__ void Embedding_59124519797196_kernel(const int* __restrict__ idx,
                                                const float* __restrict__ weight,
                                                float* __restrict__ out) {
    const int row = blockIdx.x;          // 0 .. N_ROWS-1
    const int t   = threadIdx.x;         // 0 .. 255

    const int src = idx[row];            // wave-uniform broadcast load

    const float4* __restrict__ wrow =
        reinterpret_cast<const float4*>(weight + (size_t)src * FEATURES);
    float4* __restrict__ orow =
        reinterpret_cast<float4*>(out + (size_t)row * FEATURES);

    // FEATURES/4 = 256 float4 per row == blockDim.x, so exactly one per thread.
    orow[t] = wrow[t];
}

extern "C" void kernel_launch(void* const* d_in, const int* in_sizes, int n_in,
                              void* d_out, int out_size, void* d_ws, size_t ws_size,
                              hipStream_t stream) {
    const int*   idx    = (const int*)d_in[0];
    const float* weight = (const float*)d_in[1];
    float*       out    = (float*)d_out;

    dim3 grid(N_ROWS);
    dim3 block(FEATURES / 4);  // 256 threads, one float4 each

    Embedding_59124519797196_kernel<<<grid, block, 0, stream>>>(idx, weight, out);
}